// Round 4
// baseline (427.742 us; speedup 1.0000x reference)
//
#include <hip/hip_runtime.h>
#include <math.h>

// NoisyTopKRouter: B=4, T=4096, C=2048, E=64, K=8; rows = 16384.
// (1) convert_w: split w into hi/lo bf16 packed in MFMA-fragment order;
//     also zeroes the split-K tickets (ws is re-poisoned every iter).
// (2) router_gemm: split-bf16 MFMA, K-split x4, x pre-split in LDS
//     (conflict-free pitch), B frags DIRECT from global (L2-resident).
//     Counted-wait barrier in loop (no vmcnt(0) drain). After partial
//     store: ticket atomicAdd; the LAST block per rowgroup runs the
//     epilogue in-place (rank-by-counting top-8, sparse softmax,
//     selective f64 tie repair) with a depth-2 row pipeline.
//     Partials are read hot from L2/L3; no 3rd launch, no cold ramp.

#define CDIM   2048
#define EDIM   64
#define NOUT   128
#define TOPK   8
#define NROWS  16384
#define BM     64
#define BK     32
#define KSPLIT 4
#define KQ     (CDIM / KSPLIT)   // 512
#define NIT    (KQ / BK)         // 16
#define TAU    1e-3f
#define XPS    72                // xsh pitch (shorts): 36 words -> 2-way reads (free)

typedef __attribute__((ext_vector_type(8))) short bf16x8;
typedef __attribute__((ext_vector_type(4))) float f32x4;

__device__ __forceinline__ void split8(const float4 a, const float4 b,
                                       bf16x8& h8, bf16x8& l8) {
    const float vv[8] = {a.x, a.y, a.z, a.w, b.x, b.y, b.z, b.w};
    #pragma unroll
    for (int j = 0; j < 8; ++j) {
        const __bf16 h = (__bf16)vv[j];
        const __bf16 l = (__bf16)(vv[j] - (float)h);
        h8[j] = __builtin_bit_cast(short, h);
        l8[j] = __builtin_bit_cast(short, l);
    }
}

// barrier WITHOUT vmcnt(0) drain: LDS writes made visible, global loads
// stay in flight (compiler still emits counted vmcnt for register uses).
__device__ __forceinline__ void block_sync() {
    asm volatile("s_waitcnt lgkmcnt(0)" ::: "memory");
    __builtin_amdgcn_s_barrier();
}

// wave-private LDS visibility: DS pipe is in-order per wave, lanes are
// lockstep -> a counted-wait is enough, no s_barrier needed.
__device__ __forceinline__ void wave_lds_sync() {
    asm volatile("s_waitcnt lgkmcnt(0)" ::: "memory");
}

// ---- kernel 1: pack w into MFMA-fragment order, hi/lo bf16.
// slot s = (kc*8 + cg)*64 + lane holds w[col = cg*16 + (lane&15)]
//                                    [k = kc*32 + (lane>>4)*8 + j]
__global__ __launch_bounds__(256)
void convert_w(const float* __restrict__ wr, const float* __restrict__ wn,
               short* __restrict__ whi, short* __restrict__ wlo,
               unsigned int* __restrict__ tickets) {
    const int s    = (int)blockIdx.x * 256 + (int)threadIdx.x;  // 0..32767
    if (s < NROWS / BM) tickets[s] = 0u;   // 256 rowgroup tickets
    const int lane = s & 63;
    const int cg   = (s >> 6) & 7;
    const int kc   = s >> 9;
    const int col  = cg * 16 + (lane & 15);
    const int k0   = kc * 32 + (lane >> 4) * 8;
    const float* src = (col < EDIM ? wr + (size_t)col * CDIM
                                   : wn + (size_t)(col - EDIM) * CDIM) + k0;
    const float4 a = *(const float4*)src;
    const float4 b = *(const float4*)(src + 4);
    bf16x8 h8, l8; split8(a, b, h8, l8);
    *(bf16x8*)(whi + (size_t)s * 8) = h8;
    *(bf16x8*)(wlo + (size_t)s * 8) = l8;
}

// ---- kernel 2: split-bf16 MFMA GEMM, K-split x4 + last-block epilogue
__global__ __launch_bounds__(256, 4)
void router_gemm(const float* __restrict__ x,
                 const short* __restrict__ whi,
                 const short* __restrict__ wlo,
                 const float* __restrict__ w_route,
                 const float* __restrict__ w_noise,
                 const float* __restrict__ noise,
                 float* __restrict__ part,
                 unsigned int* __restrict__ tickets,
                 float* __restrict__ out_probs,
                 float* __restrict__ out_idx)
{
    __shared__ __align__(16) short xsh[2][BM][XPS];   // 18.4 KB
    __shared__ float vals[4][64];
    __shared__ float srt[4][64];
    __shared__ unsigned int last_flag;

    const int tid  = (int)threadIdx.x;
    const int lane = tid & 63;
    const int wid  = tid >> 6;
    const int wr   = wid >> 1;          // row half (32 rows)
    const int wc   = wid & 1;           // col half (64 cols)
    const int l15  = lane & 15;
    const int q8   = (lane >> 4) * 8;
    const int q4   = (lane >> 4) * 4;
    const int qk   = (int)blockIdx.x & (KSPLIT - 1);
    const int rg   = (int)blockIdx.x >> 2;    // rowgroup 0..255
    const int row0 = rg * BM;

    const int srow = tid >> 2;          // 0..63
    const int skk  = (tid & 3) * 8;     // 0,8,16,24 (shorts)
    const float* xsrc = x + (size_t)(row0 + srow) * CDIM + qk * KQ + skk;

    f32x4 acc[2][4];
    #pragma unroll
    for (int mr = 0; mr < 2; ++mr)
        #pragma unroll
        for (int nc = 0; nc < 4; ++nc)
            acc[mr][nc] = (f32x4){0.f, 0.f, 0.f, 0.f};

    // B frags direct from global (packed, coalesced lane*16), SINGLE buffer
    bf16x8 bh[4], bl[4];
    auto loadB = [&](int it) {
        const int base = ((qk * NIT + it) * 8 + wc * 4) * 512 + lane * 8;
        #pragma unroll
        for (int nc = 0; nc < 4; ++nc) {
            bh[nc] = *(const bf16x8*)(whi + base + nc * 512);
            bl[nc] = *(const bf16x8*)(wlo + base + nc * 512);
        }
    };

    // prologue: x-chunk(0) staged + x-chunk(1) in regs (depth 2)
    {
        const float4 a = *(const float4*)xsrc;
        const float4 b = *(const float4*)(xsrc + 4);
        bf16x8 h8, l8; split8(a, b, h8, l8);
        *(bf16x8*)&xsh[0][srow][skk]      = h8;
        *(bf16x8*)&xsh[0][srow][32 + skk] = l8;
    }
    float4 pfa[2], pfb[2];
    pfa[1] = *(const float4*)(xsrc + BK);
    pfb[1] = *(const float4*)(xsrc + BK + 4);
    block_sync();

    #pragma unroll 2
    for (int it = 0; it < NIT; ++it) {
        const int cur = it & 1;
        loadB(it);                                  // L2-resident, this iter
        if (it + 2 < NIT) {                         // x two iters ahead (HBM)
            pfa[cur] = *(const float4*)(xsrc + (it + 2) * BK);
            pfb[cur] = *(const float4*)(xsrc + (it + 2) * BK + 4);
        }
        bf16x8 ah[2], al[2];
        #pragma unroll
        for (int mr = 0; mr < 2; ++mr) {
            const short* ar = &xsh[cur][wr * 32 + mr * 16 + l15][0];
            ah[mr] = *(const bf16x8*)(ar + q8);
            al[mr] = *(const bf16x8*)(ar + 32 + q8);
        }
        #pragma unroll
        for (int mr = 0; mr < 2; ++mr)
            #pragma unroll
            for (int nc = 0; nc < 4; ++nc) {
                acc[mr][nc] = __builtin_amdgcn_mfma_f32_16x16x32_bf16(ah[mr], bh[nc], acc[mr][nc], 0, 0, 0);
                acc[mr][nc] = __builtin_amdgcn_mfma_f32_16x16x32_bf16(al[mr], bh[nc], acc[mr][nc], 0, 0, 0);
                acc[mr][nc] = __builtin_amdgcn_mfma_f32_16x16x32_bf16(ah[mr], bl[nc], acc[mr][nc], 0, 0, 0);
            }
        if (it + 1 < NIT) {
            bf16x8 h8, l8; split8(pfa[cur ^ 1], pfb[cur ^ 1], h8, l8);
            *(bf16x8*)&xsh[cur ^ 1][srow][skk]      = h8;
            *(bf16x8*)&xsh[cur ^ 1][srow][32 + skk] = l8;
            block_sync();
        }
    }

    // partial store (C/D layout: row = quad*4+reg, col = lane&15)
    float* dst = part + (size_t)qk * NROWS * NOUT;
    #pragma unroll
    for (int mr = 0; mr < 2; ++mr)
        #pragma unroll
        for (int nc = 0; nc < 4; ++nc)
            #pragma unroll
            for (int g = 0; g < 4; ++g)
                dst[(size_t)(row0 + wr * 32 + mr * 16 + q4 + g) * NOUT
                    + wc * 64 + nc * 16 + l15] = acc[mr][nc][g];

    // ---- split-K ticket: last block for this rowgroup runs the epilogue
    __syncthreads();             // drains vmcnt(0): all partial stores done
    if (tid == 0) {
        __threadfence();         // release: push this XCD's L2 to coherent pt
        const unsigned int old = atomicAdd(&tickets[rg], 1u);
        last_flag = (old == KSPLIT - 1) ? 1u : 0u;
    }
    __syncthreads();
    if (!last_flag) return;
    if (tid == 0) __threadfence();   // acquire: invalidate stale L2 lines
    __syncthreads();

    // ---- epilogue: wave wid handles rows wid*16 .. wid*16+15
    const float* p0 = part;
    const float* p1 = part + (size_t)NROWS * NOUT;
    const float* p2 = part + (size_t)2 * NROWS * NOUT;
    const float* p3 = part + (size_t)3 * NROWS * NOUT;

    // depth-2 row pipeline: issue row r+1's 9 loads during row r's ranking
    float lr0[2], lr1[2], lr2[2], lr3[2];
    float ln0[2], ln1[2], ln2[2], ln3[2], lnv[2];
    auto issue_row = [&](int slot, int r) {
        const int grow = row0 + wid * 16 + r;
        const size_t ro = (size_t)grow * NOUT;
        lr0[slot] = p0[ro + lane];        lr1[slot] = p1[ro + lane];
        lr2[slot] = p2[ro + lane];        lr3[slot] = p3[ro + lane];
        ln0[slot] = p0[ro + EDIM + lane]; ln1[slot] = p1[ro + EDIM + lane];
        ln2[slot] = p2[ro + EDIM + lane]; ln3[slot] = p3[ro + EDIM + lane];
        lnv[slot] = noise[(size_t)grow * EDIM + lane];
    };
    issue_row(0, 0);

    #pragma unroll 1
    for (int r = 0; r < 16; ++r) {
        const int slot = r & 1;
        if (r + 1 < 16) issue_row(slot ^ 1, r + 1);
        const int grow = row0 + wid * 16 + r;

        const float route = (lr0[slot] + lr1[slot]) + (lr2[slot] + lr3[slot]);
        const float nz    = (ln0[slot] + ln1[slot]) + (ln2[slot] + ln3[slot]);
        const float nv    = lnv[slot];
        const float sp = fmaxf(nz, 0.f) + log1pf(expf(-fabsf(nz)));
        const float nl = route + nv * sp;

        vals[wid][lane] = nl;        // wave-private slice: no block barrier
        wave_lds_sync();

        // rank = #{j better}; "better" = (v_j > v_i) or tie with j < i
        int cnt = 0;
        #pragma unroll
        for (int jq = 0; jq < 16; ++jq) {
            const float4 v = *(const float4*)&vals[wid][jq * 4];
            const int j0 = jq * 4;
            cnt += (v.x > nl || (v.x == nl && (j0 + 0) < lane));
            cnt += (v.y > nl || (v.y == nl && (j0 + 1) < lane));
            cnt += (v.z > nl || (v.z == nl && (j0 + 2) < lane));
            cnt += (v.w > nl || (v.w == nl && (j0 + 3) < lane));
        }
        srt[wid][cnt] = nl;   // ranks are a permutation of 0..63
        wave_lds_sync();

        const float m = srt[wid][0];
        bool amb = false, flagme = false;
        float prev = m;
        #pragma unroll
        for (int t = 1; t <= TOPK; ++t) {
            const float vt = srt[wid][t];
            if (prev - vt < TAU) {
                amb = true;
                const float vb = 0.5f * (prev + vt);
                flagme = flagme || (fabsf(nl - vb) <= TAU);
            }
            prev = vt;
        }

        if (cnt < TOPK) out_idx[(size_t)grow * TOPK + cnt] = (float)lane;
        float ev = (cnt < TOPK) ? expf(nl - m) : 0.f;
        float s  = ev;
        #pragma unroll
        for (int off = 32; off >= 1; off >>= 1) s += __shfl_xor(s, off, 64);
        out_probs[(size_t)grow * EDIM + lane] = ev / s;

        if (amb) {
            // selective f64 repair: exact dots only for flagged experts
            unsigned long long mask = __ballot(flagme);
            double nld = (double)nl;
            const float* xr = x + (size_t)grow * CDIM;
            while (mask) {
                const int e = (int)__ffsll(mask) - 1;
                mask &= (mask - 1);
                double ar2 = 0.0, an = 0.0;
                const float* wrp = w_route + (size_t)e * CDIM;
                const float* wnp = w_noise + (size_t)e * CDIM;
                #pragma unroll
                for (int j = 0; j < 8; ++j) {
                    const int k = (j * 64 + lane) * 4;   // coalesced
                    const float4 xv = *(const float4*)(xr + k);
                    const float4 rv = *(const float4*)(wrp + k);
                    const float4 nq = *(const float4*)(wnp + k);
                    ar2 = fma((double)xv.x, (double)rv.x, ar2);
                    ar2 = fma((double)xv.y, (double)rv.y, ar2);
                    ar2 = fma((double)xv.z, (double)rv.z, ar2);
                    ar2 = fma((double)xv.w, (double)rv.w, ar2);
                    an  = fma((double)xv.x, (double)nq.x, an);
                    an  = fma((double)xv.y, (double)nq.y, an);
                    an  = fma((double)xv.z, (double)nq.z, an);
                    an  = fma((double)xv.w, (double)nq.w, an);
                }
                #pragma unroll
                for (int off = 32; off >= 1; off >>= 1) {
                    ar2 += __shfl_xor(ar2, off, 64);
                    an  += __shfl_xor(an, off, 64);
                }
                const double spd = fmax(an, 0.0) + log1p(exp(-fabs(an)));
                const double nve = (double)__shfl(nv, e, 64);
                const double v   = ar2 + nve * spd;
                if (lane == e) nld = v;
            }
            double workd = nld;
            int    rank2 = -1;
            double m2 = 0.0;
            #pragma unroll
            for (int t = 0; t < TOPK; ++t) {
                double bv = workd;
                int    bi = lane;
                #pragma unroll
                for (int off = 32; off >= 1; off >>= 1) {
                    const double ov = __shfl_xor(bv, off, 64);
                    const int    oi = __shfl_xor(bi, off, 64);
                    if (ov > bv || (ov == bv && oi < bi)) { bv = ov; bi = oi; }
                }
                if (t == 0) m2 = bv;
                if (lane == bi) {
                    rank2 = t;
                    workd = -INFINITY;
                    out_idx[(size_t)grow * TOPK + t] = (float)lane;
                }
            }
            float ev2 = (rank2 >= 0) ? expf((float)(nld - m2)) : 0.f;
            float s2  = ev2;
            #pragma unroll
            for (int off = 32; off >= 1; off >>= 1) s2 += __shfl_xor(s2, off, 64);
            out_probs[(size_t)grow * EDIM + lane] = ev2 / s2;
        }
    }
}

extern "C" void kernel_launch(void* const* d_in, const int* in_sizes, int n_in,
                              void* d_out, int out_size, void* d_ws, size_t ws_size,
                              hipStream_t stream)
{
    const float* x       = (const float*)d_in[0];
    const float* w_route = (const float*)d_in[1];
    const float* w_noise = (const float*)d_in[2];
    const float* noise   = (const float*)d_in[3];

    const int n_rows = in_sizes[0] / CDIM;                 // 16384
    float* out_probs = (float*)d_out;                      // (B,T,E) fp32
    float* out_idx   = out_probs + (size_t)n_rows * EDIM;  // (B,T,K) as fp32

    short* whi  = (short*)d_ws;                            // 512 KB packed hi
    short* wlo  = whi + (size_t)NOUT * CDIM;               // 512 KB packed lo
    float* part = (float*)((char*)d_ws + 2u * 1024u * 1024u); // 4 x 16384 x 128 f32
    unsigned int* tickets = (unsigned int*)((char*)d_ws + 36u * 1024u * 1024u);

    hipLaunchKernelGGL(convert_w, dim3(NOUT * CDIM / (256 * 8)), dim3(256), 0, stream,
                       w_route, w_noise, whi, wlo, tickets);
    hipLaunchKernelGGL(router_gemm, dim3((n_rows / BM) * KSPLIT), dim3(256), 0, stream,
                       x, whi, wlo, w_route, w_noise, noise, part, tickets,
                       out_probs, out_idx);
}

// Round 5
// 260.117 us; speedup vs baseline: 1.6444x; 1.6444x over previous
//
#include <hip/hip_runtime.h>
#include <math.h>

// NoisyTopKRouter: B=4, T=4096, C=2048, E=64, K=8; rows = 16384.
// (1) convert_w: split w into hi/lo bf16 packed in MFMA-fragment order.
// (2) router_gemm: BARRIER-FREE, LDS-FREE wave-autonomous split-bf16
//     MFMA. Each wave owns 32 rows x 128 cols x one K-quarter. A-frags
//     loaded DIRECT from global (lane l = row l&15, 8 contiguous floats)
//     and hi/lo-split in-register; B frags direct from L2-resident
//     packed whi/wlo (qk->XCD accidental affinity: one 256KB quarter
//     per XCD). No syncthreads anywhere: 2048 independent waves keep
//     HBM saturated. Partial store layout identical to prior rounds.
// (3) router_epilogue: rank-by-counting top-8, sparse softmax,
//     selective f64 near-tie repair (validated numerics, unchanged).

#define CDIM   2048
#define EDIM   64
#define NOUT   128
#define TOPK   8
#define NROWS  16384
#define BK     32
#define KSPLIT 4
#define KQ     (CDIM / KSPLIT)   // 512
#define NIT    (KQ / BK)         // 16
#define TAU    1e-3f

typedef __attribute__((ext_vector_type(8))) short bf16x8;
typedef __attribute__((ext_vector_type(4))) float f32x4;

__device__ __forceinline__ void split8(const float4 a, const float4 b,
                                       bf16x8& h8, bf16x8& l8) {
    const float vv[8] = {a.x, a.y, a.z, a.w, b.x, b.y, b.z, b.w};
    #pragma unroll
    for (int j = 0; j < 8; ++j) {
        const __bf16 h = (__bf16)vv[j];
        const __bf16 l = (__bf16)(vv[j] - (float)h);
        h8[j] = __builtin_bit_cast(short, h);
        l8[j] = __builtin_bit_cast(short, l);
    }
}

// wave-private LDS visibility: DS pipe is in-order per wave, lanes are
// lockstep -> a counted-wait is enough, no s_barrier needed.
__device__ __forceinline__ void wave_lds_sync() {
    asm volatile("s_waitcnt lgkmcnt(0)" ::: "memory");
}

// ---- kernel 1: pack w into MFMA-fragment order, hi/lo bf16.
// slot s = (kc*8 + cg)*64 + lane holds w[col = cg*16 + (lane&15)]
//                                    [k = kc*32 + (lane>>4)*8 + j]
__global__ __launch_bounds__(256)
void convert_w(const float* __restrict__ wr, const float* __restrict__ wn,
               short* __restrict__ whi, short* __restrict__ wlo) {
    const int s    = (int)blockIdx.x * 256 + (int)threadIdx.x;  // 0..32767
    const int lane = s & 63;
    const int cg   = (s >> 6) & 7;
    const int kc   = s >> 9;
    const int col  = cg * 16 + (lane & 15);
    const int k0   = kc * 32 + (lane >> 4) * 8;
    const float* src = (col < EDIM ? wr + (size_t)col * CDIM
                                   : wn + (size_t)(col - EDIM) * CDIM) + k0;
    const float4 a = *(const float4*)src;
    const float4 b = *(const float4*)(src + 4);
    bf16x8 h8, l8; split8(a, b, h8, l8);
    *(bf16x8*)(whi + (size_t)s * 8) = h8;
    *(bf16x8*)(wlo + (size_t)s * 8) = l8;
}

// ---- kernel 2: wave-autonomous split-bf16 MFMA GEMM -> f32 partials
__global__ __launch_bounds__(256, 2)
void router_gemm(const float* __restrict__ x,
                 const short* __restrict__ whi,
                 const short* __restrict__ wlo,
                 float* __restrict__ part)
{
    const int tid  = (int)threadIdx.x;
    const int lane = tid & 63;
    const int wid  = tid >> 6;
    const int l15  = lane & 15;
    const int q8   = (lane >> 4) * 8;
    const int q4   = (lane >> 4) * 4;
    const int bi   = (int)blockIdx.x;
    const int qk   = bi & (KSPLIT - 1);        // K-quarter; bi%8 -> XCD, so
                                               // each XCD sees ONE qk slice
    const int rowblk = (bi >> 2) * 4 + wid;    // 0..511
    const int row0   = rowblk * 32;

    // per-lane A source: row = row0 + mr*16 + (lane&15), k-base = q8
    const float* xp[2];
    xp[0] = x + (size_t)(row0 + l15) * CDIM + qk * KQ + q8;
    xp[1] = x + (size_t)(row0 + 16 + l15) * CDIM + qk * KQ + q8;

    f32x4 acc[2][8];
    #pragma unroll
    for (int mr = 0; mr < 2; ++mr)
        #pragma unroll
        for (int nc = 0; nc < 8; ++nc)
            acc[mr][nc] = (f32x4){0.f, 0.f, 0.f, 0.f};

    // x landing regs, depth 2 (slot = it&1; compile-time via unroll 2)
    float4 xa[2][2][2];   // [slot][mr][half]
    #pragma unroll
    for (int s = 0; s < 2; ++s)
        #pragma unroll
        for (int mr = 0; mr < 2; ++mr) {
            xa[s][mr][0] = *(const float4*)(xp[mr] + s * BK);
            xa[s][mr][1] = *(const float4*)(xp[mr] + s * BK + 4);
        }

    bf16x8 bh[8], bl[8];

    #pragma unroll 2
    for (int it = 0; it < NIT; ++it) {
        const int slot = it & 1;
        const int kc   = qk * NIT + it;
        // B for this iter (L2-resident packed layout, coalesced lane*16B);
        // graduated vmcnt at the MFMAs below pipelines these naturally.
        #pragma unroll
        for (int nc = 0; nc < 8; ++nc) {
            const int base = (kc * 8 + nc) * 512 + lane * 8;
            bh[nc] = *(const bf16x8*)(whi + base);
            bl[nc] = *(const bf16x8*)(wlo + base);
        }
        // consume x(it) (issued 2 iters ago; older than this iter's B, so
        // this wait does NOT drain the B loads above)
        bf16x8 ah[2], al[2];
        split8(xa[slot][0][0], xa[slot][0][1], ah[0], al[0]);
        split8(xa[slot][1][0], xa[slot][1][1], ah[1], al[1]);
        // refill freed slot with x(it+2) — stays in flight across the
        // MFMA block's B-wait (issued after B)
        if (it + 2 < NIT) {
            #pragma unroll
            for (int mr = 0; mr < 2; ++mr) {
                xa[slot][mr][0] = *(const float4*)(xp[mr] + (it + 2) * BK);
                xa[slot][mr][1] = *(const float4*)(xp[mr] + (it + 2) * BK + 4);
            }
        }
        #pragma unroll
        for (int nc = 0; nc < 8; ++nc)
            #pragma unroll
            for (int mr = 0; mr < 2; ++mr) {
                acc[mr][nc] = __builtin_amdgcn_mfma_f32_16x16x32_bf16(ah[mr], bh[nc], acc[mr][nc], 0, 0, 0);
                acc[mr][nc] = __builtin_amdgcn_mfma_f32_16x16x32_bf16(al[mr], bh[nc], acc[mr][nc], 0, 0, 0);
                acc[mr][nc] = __builtin_amdgcn_mfma_f32_16x16x32_bf16(ah[mr], bl[nc], acc[mr][nc], 0, 0, 0);
            }
    }

    // partial store (C/D layout: row = quad*4+reg, col = lane&15)
    float* dst = part + (size_t)qk * NROWS * NOUT;
    #pragma unroll
    for (int mr = 0; mr < 2; ++mr)
        #pragma unroll
        for (int nc = 0; nc < 8; ++nc)
            #pragma unroll
            for (int g = 0; g < 4; ++g)
                dst[(size_t)(row0 + mr * 16 + q4 + g) * NOUT
                    + nc * 16 + l15] = acc[mr][nc][g];
}

// ---- kernel 3: rank-by-counting epilogue; wave = one row
__global__ __launch_bounds__(256, 4)
void router_epilogue(const float* __restrict__ x,
                     const float* __restrict__ w_route,
                     const float* __restrict__ w_noise,
                     const float* __restrict__ noise,
                     const float* __restrict__ part,
                     float* __restrict__ out_probs,
                     float* __restrict__ out_idx)
{
    __shared__ float vals[4][64];
    __shared__ float srt[4][64];

    const int tid  = (int)threadIdx.x;
    const int lane = tid & 63;   // lane == expert index
    const int wid  = tid >> 6;
    const int grow = (int)blockIdx.x * 4 + wid;
    const float* p0 = part;
    const float* p1 = part + (size_t)NROWS * NOUT;
    const float* p2 = part + (size_t)2 * NROWS * NOUT;
    const float* p3 = part + (size_t)3 * NROWS * NOUT;

    const size_t ro = (size_t)grow * NOUT;
    const float route = (p0[ro + lane] + p1[ro + lane])
                      + (p2[ro + lane] + p3[ro + lane]);
    const float nz    = (p0[ro + EDIM + lane] + p1[ro + EDIM + lane])
                      + (p2[ro + EDIM + lane] + p3[ro + EDIM + lane]);
    const float nv    = noise[(size_t)grow * EDIM + lane];
    const float sp = fmaxf(nz, 0.f) + log1pf(expf(-fabsf(nz)));
    const float nl = route + nv * sp;

    vals[wid][lane] = nl;        // wave-private slice: no block barrier
    wave_lds_sync();

    // rank = #{j better than me}; "better" = (v_j > v_i) or tie with j < i
    int cnt = 0;
    #pragma unroll
    for (int jq = 0; jq < 16; ++jq) {
        const float4 v = *(const float4*)&vals[wid][jq * 4];
        const int j0 = jq * 4;
        cnt += (v.x > nl || (v.x == nl && (j0 + 0) < lane));
        cnt += (v.y > nl || (v.y == nl && (j0 + 1) < lane));
        cnt += (v.z > nl || (v.z == nl && (j0 + 2) < lane));
        cnt += (v.w > nl || (v.w == nl && (j0 + 3) < lane));
    }
    srt[wid][cnt] = nl;   // ranks are a permutation of 0..63
    wave_lds_sync();

    const float m = srt[wid][0];
    // gap scan over the 8 ranking-relevant boundaries (uniform per wave)
    bool amb = false, flagme = false;
    float prev = m;
    #pragma unroll
    for (int t = 1; t <= TOPK; ++t) {
        const float vt = srt[wid][t];
        if (prev - vt < TAU) {
            amb = true;
            const float vb = 0.5f * (prev + vt);
            flagme = flagme || (fabsf(nl - vb) <= TAU);
        }
        prev = vt;
    }

    if (cnt < TOPK) out_idx[(size_t)grow * TOPK + cnt] = (float)lane;
    float ev = (cnt < TOPK) ? expf(nl - m) : 0.f;
    float s  = ev;
    #pragma unroll
    for (int off = 32; off >= 1; off >>= 1) s += __shfl_xor(s, off, 64);
    out_probs[(size_t)grow * EDIM + lane] = ev / s;

    if (amb) {
        // selective f64 repair: exact dots only for flagged experts
        unsigned long long mask = __ballot(flagme);
        double nld = (double)nl;
        const float* xr = x + (size_t)grow * CDIM;
        while (mask) {
            const int e = (int)__ffsll(mask) - 1;
            mask &= (mask - 1);
            double ar = 0.0, an = 0.0;
            const float* wrp = w_route + (size_t)e * CDIM;
            const float* wnp = w_noise + (size_t)e * CDIM;
            #pragma unroll
            for (int j = 0; j < 8; ++j) {
                const int k = (j * 64 + lane) * 4;   // coalesced
                const float4 xv = *(const float4*)(xr + k);
                const float4 rv = *(const float4*)(wrp + k);
                const float4 nq = *(const float4*)(wnp + k);
                ar = fma((double)xv.x, (double)rv.x, ar);
                ar = fma((double)xv.y, (double)rv.y, ar);
                ar = fma((double)xv.z, (double)rv.z, ar);
                ar = fma((double)xv.w, (double)rv.w, ar);
                an = fma((double)xv.x, (double)nq.x, an);
                an = fma((double)xv.y, (double)nq.y, an);
                an = fma((double)xv.z, (double)nq.z, an);
                an = fma((double)xv.w, (double)nq.w, an);
            }
            #pragma unroll
            for (int off = 32; off >= 1; off >>= 1) {
                ar += __shfl_xor(ar, off, 64);
                an += __shfl_xor(an, off, 64);
            }
            const double spd = fmax(an, 0.0) + log1p(exp(-fabs(an)));
            const double nve = (double)__shfl(nv, e, 64);
            const double v   = ar + nve * spd;
            if (lane == e) nld = v;
        }
        double workd = nld;
        int    rank2 = -1;
        double m2 = 0.0;
        #pragma unroll
        for (int t = 0; t < TOPK; ++t) {
            double bv = workd;
            int    bi = lane;
            #pragma unroll
            for (int off = 32; off >= 1; off >>= 1) {
                const double ov = __shfl_xor(bv, off, 64);
                const int    oi = __shfl_xor(bi, off, 64);
                if (ov > bv || (ov == bv && oi < bi)) { bv = ov; bi = oi; }
            }
            if (t == 0) m2 = bv;
            if (lane == bi) {
                rank2 = t;
                workd = -INFINITY;
                out_idx[(size_t)grow * TOPK + t] = (float)lane;
            }
        }
        float ev2 = (rank2 >= 0) ? expf((float)(nld - m2)) : 0.f;
        float s2  = ev2;
        #pragma unroll
        for (int off = 32; off >= 1; off >>= 1) s2 += __shfl_xor(s2, off, 64);
        out_probs[(size_t)grow * EDIM + lane] = ev2 / s2;
    }
}

extern "C" void kernel_launch(void* const* d_in, const int* in_sizes, int n_in,
                              void* d_out, int out_size, void* d_ws, size_t ws_size,
                              hipStream_t stream)
{
    const float* x       = (const float*)d_in[0];
    const float* w_route = (const float*)d_in[1];
    const float* w_noise = (const float*)d_in[2];
    const float* noise   = (const float*)d_in[3];

    const int n_rows = in_sizes[0] / CDIM;                 // 16384
    float* out_probs = (float*)d_out;                      // (B,T,E) fp32
    float* out_idx   = out_probs + (size_t)n_rows * EDIM;  // (B,T,K) as fp32

    short* whi  = (short*)d_ws;                            // 512 KB packed hi
    short* wlo  = whi + (size_t)NOUT * CDIM;               // 512 KB packed lo
    float* part = (float*)((char*)d_ws + 2u * 1024u * 1024u); // 4 x 16384 x 128 f32

    hipLaunchKernelGGL(convert_w, dim3(NOUT * CDIM / (256 * 8)), dim3(256), 0, stream,
                       w_route, w_noise, whi, wlo);
    hipLaunchKernelGGL(router_gemm, dim3((n_rows / 32 / 4) * KSPLIT), dim3(256), 0, stream,
                       x, whi, wlo, part);
    hipLaunchKernelGGL(router_epilogue, dim3(n_rows / 4), dim3(256), 0, stream,
                       x, w_route, w_noise, noise, part, out_probs, out_idx);
}

// Round 6
// 241.762 us; speedup vs baseline: 1.7693x; 1.0759x over previous
//
#include <hip/hip_runtime.h>
#include <math.h>

// NoisyTopKRouter: B=4, T=4096, C=2048, E=64, K=8; rows = 16384.
// (1) convert_w: split w into hi/lo bf16 packed in MFMA-fragment order.
// (2) router_gemm: split-bf16 MFMA, BM=256 (512-thr, 8 waves), K-split
//     x4. B traffic amortized over 4x more rows than BM=64 (256->64 MB
//     through the L2/L3 path -- the measured ~7 TB/s cache-path ceiling
//     is the binding constraint, r5 counters). x pre-split in LDS
//     (conflict-free pitch 72), counted-wait barriers (no vmcnt(0)
//     drain), x prefetch depth 2. Grid 256 = 1 block/CU, no tail.
// (3) router_epilogue: rank-by-counting top-8, wave-private LDS sync,
//     sparse softmax, selective f64 near-tie repair (validated).

#define CDIM   2048
#define EDIM   64
#define NOUT   128
#define TOPK   8
#define NROWS  16384
#define BM     256
#define BK     32
#define KSPLIT 4
#define KQ     (CDIM / KSPLIT)   // 512
#define NIT    (KQ / BK)         // 16
#define TAU    1e-3f
#define XPS    72                // xsh pitch (shorts): 36 words -> 2-way reads (free)

typedef __attribute__((ext_vector_type(8))) short bf16x8;
typedef __attribute__((ext_vector_type(4))) float f32x4;

__device__ __forceinline__ void split8(const float4 a, const float4 b,
                                       bf16x8& h8, bf16x8& l8) {
    const float vv[8] = {a.x, a.y, a.z, a.w, b.x, b.y, b.z, b.w};
    #pragma unroll
    for (int j = 0; j < 8; ++j) {
        const __bf16 h = (__bf16)vv[j];
        const __bf16 l = (__bf16)(vv[j] - (float)h);
        h8[j] = __builtin_bit_cast(short, h);
        l8[j] = __builtin_bit_cast(short, l);
    }
}

// barrier WITHOUT vmcnt(0) drain: LDS writes made visible, global loads
// stay in flight (compiler still emits counted vmcnt for register uses).
__device__ __forceinline__ void block_sync() {
    asm volatile("s_waitcnt lgkmcnt(0)" ::: "memory");
    __builtin_amdgcn_s_barrier();
}

// wave-private LDS visibility: DS pipe is in-order per wave, lanes are
// lockstep -> a counted-wait is enough, no s_barrier needed.
__device__ __forceinline__ void wave_lds_sync() {
    asm volatile("s_waitcnt lgkmcnt(0)" ::: "memory");
}

// ---- kernel 1: pack w into MFMA-fragment order, hi/lo bf16.
// slot s = (kc*8 + cg)*64 + lane holds w[col = cg*16 + (lane&15)]
//                                    [k = kc*32 + (lane>>4)*8 + j]
__global__ __launch_bounds__(256)
void convert_w(const float* __restrict__ wr, const float* __restrict__ wn,
               short* __restrict__ whi, short* __restrict__ wlo) {
    const int s    = (int)blockIdx.x * 256 + (int)threadIdx.x;  // 0..32767
    const int lane = s & 63;
    const int cg   = (s >> 6) & 7;
    const int kc   = s >> 9;
    const int col  = cg * 16 + (lane & 15);
    const int k0   = kc * 32 + (lane >> 4) * 8;
    const float* src = (col < EDIM ? wr + (size_t)col * CDIM
                                   : wn + (size_t)(col - EDIM) * CDIM) + k0;
    const float4 a = *(const float4*)src;
    const float4 b = *(const float4*)(src + 4);
    bf16x8 h8, l8; split8(a, b, h8, l8);
    *(bf16x8*)(whi + (size_t)s * 8) = h8;
    *(bf16x8*)(wlo + (size_t)s * 8) = l8;
}

// ---- kernel 2: split-bf16 MFMA GEMM, BM=256, K-split x4 -> f32 partials
__global__ __launch_bounds__(512, 2)
void router_gemm(const float* __restrict__ x,
                 const short* __restrict__ whi,
                 const short* __restrict__ wlo,
                 float* __restrict__ part)
{
    __shared__ __align__(16) short xsh[2][BM][XPS];   // 72 KB

    const int tid  = (int)threadIdx.x;
    const int lane = tid & 63;
    const int wid  = tid >> 6;          // 0..7
    const int wr   = wid >> 1;          // row quarter (64 rows)
    const int wc   = wid & 1;           // col half (64 cols)
    const int l15  = lane & 15;
    const int q8   = (lane >> 4) * 8;
    const int q4   = (lane >> 4) * 4;
    const int qk   = (int)blockIdx.x & (KSPLIT - 1);
    const int row0 = ((int)blockIdx.x >> 2) * BM;

    const int srow = tid >> 1;          // 0..255
    const int skk  = (tid & 1) * 16;    // 0 or 16 (floats == shorts here)
    const float* xsrc = x + (size_t)(row0 + srow) * CDIM + qk * KQ + skk;

    f32x4 acc[4][4];
    #pragma unroll
    for (int mr = 0; mr < 4; ++mr)
        #pragma unroll
        for (int nc = 0; nc < 4; ++nc)
            acc[mr][nc] = (f32x4){0.f, 0.f, 0.f, 0.f};

    // B frags direct from global (packed, coalesced lane*16), SINGLE buffer
    // (issued at iter top; MFMA's counted vmcnt waits only on these; the
    // later-issued x loads stay in flight across the wait and the barrier).
    // Per iter the 16KB B tile is fetched once into L1 and reused by the
    // four wr-waves of the same wc.
    bf16x8 bh[4], bl[4];
    auto loadB = [&](int it) {
        const int base = ((qk * NIT + it) * 8 + wc * 4) * 512 + lane * 8;
        #pragma unroll
        for (int nc = 0; nc < 4; ++nc) {
            bh[nc] = *(const bf16x8*)(whi + base + nc * 512);
            bl[nc] = *(const bf16x8*)(wlo + base + nc * 512);
        }
    };

    // staging: thread covers 16 floats (half a row-chunk): 4x float4
    auto stage = [&](int buf, const float4 v0, const float4 v1,
                     const float4 v2, const float4 v3) {
        bf16x8 h8, l8;
        split8(v0, v1, h8, l8);
        *(bf16x8*)&xsh[buf][srow][skk]          = h8;
        *(bf16x8*)&xsh[buf][srow][32 + skk]     = l8;
        split8(v2, v3, h8, l8);
        *(bf16x8*)&xsh[buf][srow][skk + 8]      = h8;
        *(bf16x8*)&xsh[buf][srow][32 + skk + 8] = l8;
    };

    // prologue: x-chunk(0) staged + x-chunk(1) in regs (depth 2)
    stage(0, *(const float4*)xsrc,       *(const float4*)(xsrc + 4),
             *(const float4*)(xsrc + 8), *(const float4*)(xsrc + 12));
    float4 pf[2][4];
    #pragma unroll
    for (int v = 0; v < 4; ++v)
        pf[1][v] = *(const float4*)(xsrc + BK + v * 4);
    block_sync();

    #pragma unroll 2
    for (int it = 0; it < NIT; ++it) {
        const int cur = it & 1;
        loadB(it);                                  // L2-resident, this iter
        if (it + 2 < NIT) {                         // x two iters ahead (HBM)
            #pragma unroll
            for (int v = 0; v < 4; ++v)
                pf[cur][v] = *(const float4*)(xsrc + (it + 2) * BK + v * 4);
        }
        bf16x8 ah[4], al[4];
        #pragma unroll
        for (int mr = 0; mr < 4; ++mr) {
            const short* ar = &xsh[cur][wr * 64 + mr * 16 + l15][0];
            ah[mr] = *(const bf16x8*)(ar + q8);
            al[mr] = *(const bf16x8*)(ar + 32 + q8);
        }
        #pragma unroll
        for (int mr = 0; mr < 4; ++mr)
            #pragma unroll
            for (int nc = 0; nc < 4; ++nc) {
                acc[mr][nc] = __builtin_amdgcn_mfma_f32_16x16x32_bf16(ah[mr], bh[nc], acc[mr][nc], 0, 0, 0);
                acc[mr][nc] = __builtin_amdgcn_mfma_f32_16x16x32_bf16(al[mr], bh[nc], acc[mr][nc], 0, 0, 0);
                acc[mr][nc] = __builtin_amdgcn_mfma_f32_16x16x32_bf16(ah[mr], bl[nc], acc[mr][nc], 0, 0, 0);
            }
        if (it + 1 < NIT) {
            // x chunk it+1 was issued at iter it-1 (or prologue)
            stage(cur ^ 1, pf[cur ^ 1][0], pf[cur ^ 1][1],
                           pf[cur ^ 1][2], pf[cur ^ 1][3]);
            block_sync();
        }
    }

    // partial store (C/D layout: row = quad*4+reg, col = lane&15)
    float* dst = part + (size_t)qk * NROWS * NOUT;
    #pragma unroll
    for (int mr = 0; mr < 4; ++mr)
        #pragma unroll
        for (int nc = 0; nc < 4; ++nc)
            #pragma unroll
            for (int g = 0; g < 4; ++g)
                dst[(size_t)(row0 + wr * 64 + mr * 16 + q4 + g) * NOUT
                    + wc * 64 + nc * 16 + l15] = acc[mr][nc][g];
}

// ---- kernel 3: rank-by-counting epilogue; wave = one row
__global__ __launch_bounds__(256, 4)
void router_epilogue(const float* __restrict__ x,
                     const float* __restrict__ w_route,
                     const float* __restrict__ w_noise,
                     const float* __restrict__ noise,
                     const float* __restrict__ part,
                     float* __restrict__ out_probs,
                     float* __restrict__ out_idx)
{
    __shared__ float vals[4][64];
    __shared__ float srt[4][64];

    const int tid  = (int)threadIdx.x;
    const int lane = tid & 63;   // lane == expert index
    const int wid  = tid >> 6;
    const int grow = (int)blockIdx.x * 4 + wid;
    const float* p0 = part;
    const float* p1 = part + (size_t)NROWS * NOUT;
    const float* p2 = part + (size_t)2 * NROWS * NOUT;
    const float* p3 = part + (size_t)3 * NROWS * NOUT;

    const size_t ro = (size_t)grow * NOUT;
    const float route = (p0[ro + lane] + p1[ro + lane])
                      + (p2[ro + lane] + p3[ro + lane]);
    const float nz    = (p0[ro + EDIM + lane] + p1[ro + EDIM + lane])
                      + (p2[ro + EDIM + lane] + p3[ro + EDIM + lane]);
    const float nv    = noise[(size_t)grow * EDIM + lane];
    const float sp = fmaxf(nz, 0.f) + log1pf(expf(-fabsf(nz)));
    const float nl = route + nv * sp;

    vals[wid][lane] = nl;        // wave-private slice: no block barrier
    wave_lds_sync();

    // rank = #{j better than me}; "better" = (v_j > v_i) or tie with j < i
    int cnt = 0;
    #pragma unroll
    for (int jq = 0; jq < 16; ++jq) {
        const float4 v = *(const float4*)&vals[wid][jq * 4];
        const int j0 = jq * 4;
        cnt += (v.x > nl || (v.x == nl && (j0 + 0) < lane));
        cnt += (v.y > nl || (v.y == nl && (j0 + 1) < lane));
        cnt += (v.z > nl || (v.z == nl && (j0 + 2) < lane));
        cnt += (v.w > nl || (v.w == nl && (j0 + 3) < lane));
    }
    srt[wid][cnt] = nl;   // ranks are a permutation of 0..63
    wave_lds_sync();

    const float m = srt[wid][0];
    // gap scan over the 8 ranking-relevant boundaries (uniform per wave)
    bool amb = false, flagme = false;
    float prev = m;
    #pragma unroll
    for (int t = 1; t <= TOPK; ++t) {
        const float vt = srt[wid][t];
        if (prev - vt < TAU) {
            amb = true;
            const float vb = 0.5f * (prev + vt);
            flagme = flagme || (fabsf(nl - vb) <= TAU);
        }
        prev = vt;
    }

    if (cnt < TOPK) out_idx[(size_t)grow * TOPK + cnt] = (float)lane;
    float ev = (cnt < TOPK) ? expf(nl - m) : 0.f;
    float s  = ev;
    #pragma unroll
    for (int off = 32; off >= 1; off >>= 1) s += __shfl_xor(s, off, 64);
    out_probs[(size_t)grow * EDIM + lane] = ev / s;

    if (amb) {
        // selective f64 repair: exact dots only for flagged experts
        unsigned long long mask = __ballot(flagme);
        double nld = (double)nl;
        const float* xr = x + (size_t)grow * CDIM;
        while (mask) {
            const int e = (int)__ffsll(mask) - 1;
            mask &= (mask - 1);
            double ar = 0.0, an = 0.0;
            const float* wrp = w_route + (size_t)e * CDIM;
            const float* wnp = w_noise + (size_t)e * CDIM;
            #pragma unroll
            for (int j = 0; j < 8; ++j) {
                const int k = (j * 64 + lane) * 4;   // coalesced
                const float4 xv = *(const float4*)(xr + k);
                const float4 rv = *(const float4*)(wrp + k);
                const float4 nq = *(const float4*)(wnp + k);
                ar = fma((double)xv.x, (double)rv.x, ar);
                ar = fma((double)xv.y, (double)rv.y, ar);
                ar = fma((double)xv.z, (double)rv.z, ar);
                ar = fma((double)xv.w, (double)rv.w, ar);
                an = fma((double)xv.x, (double)nq.x, an);
                an = fma((double)xv.y, (double)nq.y, an);
                an = fma((double)xv.z, (double)nq.z, an);
                an = fma((double)xv.w, (double)nq.w, an);
            }
            #pragma unroll
            for (int off = 32; off >= 1; off >>= 1) {
                ar += __shfl_xor(ar, off, 64);
                an += __shfl_xor(an, off, 64);
            }
            const double spd = fmax(an, 0.0) + log1p(exp(-fabs(an)));
            const double nve = (double)__shfl(nv, e, 64);
            const double v   = ar + nve * spd;
            if (lane == e) nld = v;
        }
        double workd = nld;
        int    rank2 = -1;
        double m2 = 0.0;
        #pragma unroll
        for (int t = 0; t < TOPK; ++t) {
            double bv = workd;
            int    bi = lane;
            #pragma unroll
            for (int off = 32; off >= 1; off >>= 1) {
                const double ov = __shfl_xor(bv, off, 64);
                const int    oi = __shfl_xor(bi, off, 64);
                if (ov > bv || (ov == bv && oi < bi)) { bv = ov; bi = oi; }
            }
            if (t == 0) m2 = bv;
            if (lane == bi) {
                rank2 = t;
                workd = -INFINITY;
                out_idx[(size_t)grow * TOPK + t] = (float)lane;
            }
        }
        float ev2 = (rank2 >= 0) ? expf((float)(nld - m2)) : 0.f;
        float s2  = ev2;
        #pragma unroll
        for (int off = 32; off >= 1; off >>= 1) s2 += __shfl_xor(s2, off, 64);
        out_probs[(size_t)grow * EDIM + lane] = ev2 / s2;
    }
}

extern "C" void kernel_launch(void* const* d_in, const int* in_sizes, int n_in,
                              void* d_out, int out_size, void* d_ws, size_t ws_size,
                              hipStream_t stream)
{
    const float* x       = (const float*)d_in[0];
    const float* w_route = (const float*)d_in[1];
    const float* w_noise = (const float*)d_in[2];
    const float* noise   = (const float*)d_in[3];

    const int n_rows = in_sizes[0] / CDIM;                 // 16384
    float* out_probs = (float*)d_out;                      // (B,T,E) fp32
    float* out_idx   = out_probs + (size_t)n_rows * EDIM;  // (B,T,K) as fp32

    short* whi  = (short*)d_ws;                            // 512 KB packed hi
    short* wlo  = whi + (size_t)NOUT * CDIM;               // 512 KB packed lo
    float* part = (float*)((char*)d_ws + 2u * 1024u * 1024u); // 4 x 16384 x 128 f32

    hipLaunchKernelGGL(convert_w, dim3(NOUT * CDIM / (256 * 8)), dim3(256), 0, stream,
                       w_route, w_noise, whi, wlo);
    hipLaunchKernelGGL(router_gemm, dim3((n_rows / BM) * KSPLIT), dim3(512), 0, stream,
                       x, whi, wlo, part);
    hipLaunchKernelGGL(router_epilogue, dim3(n_rows / 4), dim3(256), 0, stream,
                       x, w_route, w_noise, noise, part, out_probs, out_idx);
}

// Round 7
// 240.346 us; speedup vs baseline: 1.7797x; 1.0059x over previous
//
#include <hip/hip_runtime.h>
#include <math.h>

// NoisyTopKRouter: B=4, T=4096, C=2048, E=64, K=8; rows = 16384.
// (1) convert_w: split w into hi/lo bf16 packed in MFMA-fragment order.
// (2) router_gemm: split-bf16 MFMA, BM=32, BK=128 (DRAM-page-friendly:
//     each row's K-slice fetched as ONE 512B contiguous burst), KSPLIT=4.
//     128-thr blocks, launch_bounds(128,4): 8 blocks/CU, grid 2048 fully
//     resident (4 waves/SIMD), zero tail. Single-buffer LDS + depth-1
//     register prefetch; counted-wait barriers (no vmcnt(0) drain).
//     MFMA k-order/accumulation bit-identical to validated r3/r6.
// (3) router_epilogue: part re-laid out row-interleaved [row][qk*128]
//     (pitch 512) -> ONE contiguous 2KB read per row instead of 4
//     scattered quarters. Rank-by-counting top-8, wave-private LDS
//     sync, sparse softmax, selective f64 near-tie repair (validated).

#define CDIM   2048
#define EDIM   64
#define NOUT   128
#define POUT   512               // part row pitch: 4 quarters x 128
#define TOPK   8
#define NROWS  16384
#define BM     32
#define BK     128               // floats per stage = 4 MFMA k-chunks
#define KSPLIT 4
#define KQ     (CDIM / KSPLIT)   // 512
#define NIT    (KQ / BK)         // 4
#define TAU    1e-3f
#define XPS    72                // slab row pitch (shorts): hi[32]|lo[32]|pad

typedef __attribute__((ext_vector_type(8))) short bf16x8;
typedef __attribute__((ext_vector_type(4))) float f32x4;

__device__ __forceinline__ void split8(const float4 a, const float4 b,
                                       bf16x8& h8, bf16x8& l8) {
    const float vv[8] = {a.x, a.y, a.z, a.w, b.x, b.y, b.z, b.w};
    #pragma unroll
    for (int j = 0; j < 8; ++j) {
        const __bf16 h = (__bf16)vv[j];
        const __bf16 l = (__bf16)(vv[j] - (float)h);
        h8[j] = __builtin_bit_cast(short, h);
        l8[j] = __builtin_bit_cast(short, l);
    }
}

// barrier WITHOUT vmcnt(0) drain: LDS writes made visible, global loads
// stay in flight (compiler still emits counted vmcnt for register uses).
__device__ __forceinline__ void block_sync() {
    asm volatile("s_waitcnt lgkmcnt(0)" ::: "memory");
    __builtin_amdgcn_s_barrier();
}

// wave-private LDS visibility: DS pipe is in-order per wave, lanes are
// lockstep -> a counted-wait is enough, no s_barrier needed.
__device__ __forceinline__ void wave_lds_sync() {
    asm volatile("s_waitcnt lgkmcnt(0)" ::: "memory");
}

// ---- kernel 1: pack w into MFMA-fragment order, hi/lo bf16.
// slot s = (kc*8 + cg)*64 + lane holds w[col = cg*16 + (lane&15)]
//                                    [k = kc*32 + (lane>>4)*8 + j]
__global__ __launch_bounds__(256)
void convert_w(const float* __restrict__ wr, const float* __restrict__ wn,
               short* __restrict__ whi, short* __restrict__ wlo) {
    const int s    = (int)blockIdx.x * 256 + (int)threadIdx.x;  // 0..32767
    const int lane = s & 63;
    const int cg   = (s >> 6) & 7;
    const int kc   = s >> 9;
    const int col  = cg * 16 + (lane & 15);
    const int k0   = kc * 32 + (lane >> 4) * 8;
    const float* src = (col < EDIM ? wr + (size_t)col * CDIM
                                   : wn + (size_t)(col - EDIM) * CDIM) + k0;
    const float4 a = *(const float4*)src;
    const float4 b = *(const float4*)(src + 4);
    bf16x8 h8, l8; split8(a, b, h8, l8);
    *(bf16x8*)(whi + (size_t)s * 8) = h8;
    *(bf16x8*)(wlo + (size_t)s * 8) = l8;
}

// ---- kernel 2: split-bf16 MFMA GEMM, BM=32/BK=128, K-split x4
__global__ __launch_bounds__(128, 4)
void router_gemm(const float* __restrict__ x,
                 const short* __restrict__ whi,
                 const short* __restrict__ wlo,
                 float* __restrict__ part)
{
    __shared__ __align__(16) short xsh[4][BM][XPS];   // 18.4 KB (4 kc slabs)

    const int tid  = (int)threadIdx.x;
    const int lane = tid & 63;
    const int wc   = tid >> 6;          // 0..1: col half (64 cols)
    const int l15  = lane & 15;
    const int q8   = (lane >> 4) * 8;
    const int q4   = (lane >> 4) * 4;
    const int bi   = (int)blockIdx.x;
    const int qk   = bi & (KSPLIT - 1);
    const int row0 = (bi >> 2) * BM;

    // staging: thread -> (row = tid>>2, slab j = tid&3), 32 contiguous
    // floats = 128B; 4 threads/row issued together = 512B/row burst.
    const int srow = tid >> 2;          // 0..31
    const int sj   = tid & 3;           // kc-slab within stage
    const float* xsrc = x + (size_t)(row0 + srow) * CDIM + qk * KQ + sj * 32;

    f32x4 acc[2][4];
    #pragma unroll
    for (int mr = 0; mr < 2; ++mr)
        #pragma unroll
        for (int nc = 0; nc < 4; ++nc)
            acc[mr][nc] = (f32x4){0.f, 0.f, 0.f, 0.f};

    // depth-1 register prefetch: one stage (32 floats) in flight
    float4 pf[8];
    auto issue = [&](int it) {
        #pragma unroll
        for (int v = 0; v < 8; ++v)
            pf[v] = *(const float4*)(xsrc + it * BK + v * 4);
    };
    auto write_pf = [&]() {
        #pragma unroll
        for (int h = 0; h < 4; ++h) {
            bf16x8 h8, l8; split8(pf[2 * h], pf[2 * h + 1], h8, l8);
            *(bf16x8*)&xsh[sj][srow][h * 8]      = h8;
            *(bf16x8*)&xsh[sj][srow][32 + h * 8] = l8;
        }
    };

    // B frags direct from global (packed, coalesced lane*16), per kc
    bf16x8 bh[4], bl[4];
    auto loadB = [&](int kcq) {   // kcq = k-chunk within this quarter, 0..15
        const int base = ((qk * 16 + kcq) * 8 + wc * 4) * 512 + lane * 8;
        #pragma unroll
        for (int nc = 0; nc < 4; ++nc) {
            bh[nc] = *(const bf16x8*)(whi + base + nc * 512);
            bl[nc] = *(const bf16x8*)(wlo + base + nc * 512);
        }
    };

    // prologue: stage(0) -> LDS; stage(1) -> regs
    issue(0);
    write_pf();
    issue(1);
    block_sync();

    #pragma unroll
    for (int it = 0; it < NIT; ++it) {
        // compute: 4 kc slabs from LDS (written at previous stage phase)
        #pragma unroll
        for (int j = 0; j < 4; ++j) {
            loadB(it * 4 + j);
            bf16x8 ah[2], al[2];
            ah[0] = *(const bf16x8*)(&xsh[j][l15][q8]);
            al[0] = *(const bf16x8*)(&xsh[j][l15][32 + q8]);
            ah[1] = *(const bf16x8*)(&xsh[j][16 + l15][q8]);
            al[1] = *(const bf16x8*)(&xsh[j][16 + l15][32 + q8]);
            #pragma unroll
            for (int mr = 0; mr < 2; ++mr)
                #pragma unroll
                for (int nc = 0; nc < 4; ++nc) {
                    acc[mr][nc] = __builtin_amdgcn_mfma_f32_16x16x32_bf16(ah[mr], bh[nc], acc[mr][nc], 0, 0, 0);
                    acc[mr][nc] = __builtin_amdgcn_mfma_f32_16x16x32_bf16(al[mr], bh[nc], acc[mr][nc], 0, 0, 0);
                    acc[mr][nc] = __builtin_amdgcn_mfma_f32_16x16x32_bf16(ah[mr], bl[nc], acc[mr][nc], 0, 0, 0);
                }
        }
        if (it + 1 < NIT) {
            block_sync();            // all waves done reading xsh
            write_pf();              // stage x(it+1) (vmcnt waits on pf)
            if (it + 2 < NIT) issue(it + 2);
            block_sync();            // writes visible
        }
    }

    // partial store, row-interleaved part layout [row][qk*128 + col]
    // (C/D layout: row = quad*4+reg, col = lane&15)
    #pragma unroll
    for (int mr = 0; mr < 2; ++mr)
        #pragma unroll
        for (int nc = 0; nc < 4; ++nc)
            #pragma unroll
            for (int g = 0; g < 4; ++g)
                part[(size_t)(row0 + mr * 16 + q4 + g) * POUT
                     + qk * NOUT + wc * 64 + nc * 16 + l15] = acc[mr][nc][g];
}

// ---- kernel 3: rank-by-counting epilogue; wave = one row
__global__ __launch_bounds__(256, 4)
void router_epilogue(const float* __restrict__ x,
                     const float* __restrict__ w_route,
                     const float* __restrict__ w_noise,
                     const float* __restrict__ noise,
                     const float* __restrict__ part,
                     float* __restrict__ out_probs,
                     float* __restrict__ out_idx)
{
    __shared__ float vals[4][64];
    __shared__ float srt[4][64];

    const int tid  = (int)threadIdx.x;
    const int lane = tid & 63;   // lane == expert index
    const int wid  = tid >> 6;
    const int grow = (int)blockIdx.x * 4 + wid;

    // one contiguous 2KB row of part: 4 quarters x (route[64]|noise[64])
    const size_t ro = (size_t)grow * POUT;
    const float route = (part[ro + lane]              + part[ro + NOUT + lane])
                      + (part[ro + 2 * NOUT + lane]   + part[ro + 3 * NOUT + lane]);
    const float nz    = (part[ro + EDIM + lane]            + part[ro + NOUT + EDIM + lane])
                      + (part[ro + 2 * NOUT + EDIM + lane] + part[ro + 3 * NOUT + EDIM + lane]);
    const float nv    = noise[(size_t)grow * EDIM + lane];
    const float sp = fmaxf(nz, 0.f) + log1pf(expf(-fabsf(nz)));
    const float nl = route + nv * sp;

    vals[wid][lane] = nl;        // wave-private slice: no block barrier
    wave_lds_sync();

    // rank = #{j better than me}; "better" = (v_j > v_i) or tie with j < i
    int cnt = 0;
    #pragma unroll
    for (int jq = 0; jq < 16; ++jq) {
        const float4 v = *(const float4*)&vals[wid][jq * 4];
        const int j0 = jq * 4;
        cnt += (v.x > nl || (v.x == nl && (j0 + 0) < lane));
        cnt += (v.y > nl || (v.y == nl && (j0 + 1) < lane));
        cnt += (v.z > nl || (v.z == nl && (j0 + 2) < lane));
        cnt += (v.w > nl || (v.w == nl && (j0 + 3) < lane));
    }
    srt[wid][cnt] = nl;   // ranks are a permutation of 0..63
    wave_lds_sync();

    const float m = srt[wid][0];
    // gap scan over the 8 ranking-relevant boundaries (uniform per wave)
    bool amb = false, flagme = false;
    float prev = m;
    #pragma unroll
    for (int t = 1; t <= TOPK; ++t) {
        const float vt = srt[wid][t];
        if (prev - vt < TAU) {
            amb = true;
            const float vb = 0.5f * (prev + vt);
            flagme = flagme || (fabsf(nl - vb) <= TAU);
        }
        prev = vt;
    }

    if (cnt < TOPK) out_idx[(size_t)grow * TOPK + cnt] = (float)lane;
    float ev = (cnt < TOPK) ? expf(nl - m) : 0.f;
    float s  = ev;
    #pragma unroll
    for (int off = 32; off >= 1; off >>= 1) s += __shfl_xor(s, off, 64);
    out_probs[(size_t)grow * EDIM + lane] = ev / s;

    if (amb) {
        // selective f64 repair: exact dots only for flagged experts
        unsigned long long mask = __ballot(flagme);
        double nld = (double)nl;
        const float* xr = x + (size_t)grow * CDIM;
        while (mask) {
            const int e = (int)__ffsll(mask) - 1;
            mask &= (mask - 1);
            double ar = 0.0, an = 0.0;
            const float* wrp = w_route + (size_t)e * CDIM;
            const float* wnp = w_noise + (size_t)e * CDIM;
            #pragma unroll
            for (int j = 0; j < 8; ++j) {
                const int k = (j * 64 + lane) * 4;   // coalesced
                const float4 xv = *(const float4*)(xr + k);
                const float4 rv = *(const float4*)(wrp + k);
                const float4 nq = *(const float4*)(wnp + k);
                ar = fma((double)xv.x, (double)rv.x, ar);
                ar = fma((double)xv.y, (double)rv.y, ar);
                ar = fma((double)xv.z, (double)rv.z, ar);
                ar = fma((double)xv.w, (double)rv.w, ar);
                an = fma((double)xv.x, (double)nq.x, an);
                an = fma((double)xv.y, (double)nq.y, an);
                an = fma((double)xv.z, (double)nq.z, an);
                an = fma((double)xv.w, (double)nq.w, an);
            }
            #pragma unroll
            for (int off = 32; off >= 1; off >>= 1) {
                ar += __shfl_xor(ar, off, 64);
                an += __shfl_xor(an, off, 64);
            }
            const double spd = fmax(an, 0.0) + log1p(exp(-fabs(an)));
            const double nve = (double)__shfl(nv, e, 64);
            const double v   = ar + nve * spd;
            if (lane == e) nld = v;
        }
        double workd = nld;
        int    rank2 = -1;
        double m2 = 0.0;
        #pragma unroll
        for (int t = 0; t < TOPK; ++t) {
            double bv = workd;
            int    bi = lane;
            #pragma unroll
            for (int off = 32; off >= 1; off >>= 1) {
                const double ov = __shfl_xor(bv, off, 64);
                const int    oi = __shfl_xor(bi, off, 64);
                if (ov > bv || (ov == bv && oi < bi)) { bv = ov; bi = oi; }
            }
            if (t == 0) m2 = bv;
            if (lane == bi) {
                rank2 = t;
                workd = -INFINITY;
                out_idx[(size_t)grow * TOPK + t] = (float)lane;
            }
        }
        float ev2 = (rank2 >= 0) ? expf((float)(nld - m2)) : 0.f;
        float s2  = ev2;
        #pragma unroll
        for (int off = 32; off >= 1; off >>= 1) s2 += __shfl_xor(s2, off, 64);
        out_probs[(size_t)grow * EDIM + lane] = ev2 / s2;
    }
}

extern "C" void kernel_launch(void* const* d_in, const int* in_sizes, int n_in,
                              void* d_out, int out_size, void* d_ws, size_t ws_size,
                              hipStream_t stream)
{
    const float* x       = (const float*)d_in[0];
    const float* w_route = (const float*)d_in[1];
    const float* w_noise = (const float*)d_in[2];
    const float* noise   = (const float*)d_in[3];

    const int n_rows = in_sizes[0] / CDIM;                 // 16384
    float* out_probs = (float*)d_out;                      // (B,T,E) fp32
    float* out_idx   = out_probs + (size_t)n_rows * EDIM;  // (B,T,K) as fp32

    short* whi  = (short*)d_ws;                            // 512 KB packed hi
    short* wlo  = whi + (size_t)NOUT * CDIM;               // 512 KB packed lo
    float* part = (float*)((char*)d_ws + 2u * 1024u * 1024u); // 16384 x 512 f32

    hipLaunchKernelGGL(convert_w, dim3(NOUT * CDIM / (256 * 8)), dim3(256), 0, stream,
                       w_route, w_noise, whi, wlo);
    hipLaunchKernelGGL(router_gemm, dim3((n_rows / BM) * KSPLIT), dim3(128), 0, stream,
                       x, whi, wlo, part);
    hipLaunchKernelGGL(router_epilogue, dim3(n_rows / 4), dim3(256), 0, stream,
                       x, w_route, w_noise, noise, part, out_probs, out_idx);
}